// Round 2
// baseline (1020.687 us; speedup 1.0000x reference)
//
#include <hip/hip_runtime.h>

typedef unsigned short u16;
typedef unsigned int u32;

// ---------- bf16 helpers (bit-level, RNE) ----------
__device__ __forceinline__ float bfl(u32 u) { union { u32 i; float f; } v; v.i = u << 16; return v.f; }
__device__ __forceinline__ float bfh(u32 u) { union { u32 i; float f; } v; v.i = u & 0xffff0000u; return v.f; }
__device__ __forceinline__ float bf2f(u16 u) { union { u32 i; float f; } v; v.i = ((u32)u) << 16; return v.f; }
__device__ __forceinline__ u16 f2bf(float f) {
    union { float f; u32 i; } v; v.f = f;
    u32 r = v.i + 0x7fffu + ((v.i >> 16) & 1u);
    return (u16)(r >> 16);
}

// ---------- dtype detection (device-side, no host sync) ----------
// flags[0] = inputs are fp32 (else bf16); flags[1] = edge_index is int64 (else int32)
// ((float*)flags)[2] = log_tau as fp32
__global__ void k_detect(const u32* __restrict__ xw, const int* __restrict__ eiw,
                         const void* __restrict__ ltau, int* __restrict__ flags,
                         int xwords, int E) {
    __shared__ int cf32, ci64nz;
    if (threadIdx.x == 0) { cf32 = 0; ci64nz = 0; }
    __syncthreads();
    int t = threadIdx.x;             // 256 threads
    int xs = xwords / 256;
    u32 w = xw[(size_t)t * xs];
    int e = (int)((w >> 23) & 0xFFu);
    if (e >= 100 && e <= 140) atomicAdd(&cf32, 1);
    int es = E / 256;
    int hw = eiw[2 * (size_t)t * es + 1];   // odd int32 position
    if (hw != 0) atomicAdd(&ci64nz, 1);
    __syncthreads();
    if (t == 0) {
        int f32 = (cf32 >= 192) ? 1 : 0;
        flags[0] = f32;
        flags[1] = (ci64nz == 0) ? 1 : 0;
        ((float*)flags)[2] = f32 ? ((const float*)ltau)[0] : bf2f(((const u16*)ltau)[0]);
    }
}

// ---------- extract src/dst as int32 regardless of edge width ----------
__global__ void k_edges(const int* __restrict__ ei, int* __restrict__ src, int* __restrict__ dst,
                        int e, const int* __restrict__ flags) {
    int i = blockIdx.x * 256 + threadIdx.x;
    if (i >= e) return;
    if (flags[1]) { src[i] = ei[2 * i]; dst[i] = ei[2 * (e + i)]; }   // int64 low words
    else          { src[i] = ei[i];     dst[i] = ei[e + i]; }
}

// ---------- graph prep ----------
__global__ void k_deginit(int* deg, int n) {
    int i = blockIdx.x * 256 + threadIdx.x;
    if (i < n) deg[i] = 1;           // self-loop
}
__global__ void k_degcount(const int* __restrict__ dst, int* deg, int e) {
    int i = blockIdx.x * 256 + threadIdx.x;
    if (i < e) atomicAdd(&deg[dst[i]], 1);
}
__global__ void k_dinv(const int* __restrict__ deg, float* dinv, int n) {
    int i = blockIdx.x * 256 + threadIdx.x;
    if (i < n) dinv[i] = rsqrtf((float)deg[i]);
}
__global__ void k_blocksum(const int* __restrict__ deg, int* bsum, int n) {
    int b = blockIdx.x, t = threadIdx.x;
    int base = b * 1024 + t * 4;
    int s = 0;
#pragma unroll
    for (int j = 0; j < 4; j++) { int i = base + j; if (i < n) s += deg[i] - 1; }
    for (int d = 32; d; d >>= 1) s += __shfl_down(s, d);
    __shared__ int ws[4];
    int lane = t & 63, w = t >> 6;
    if (lane == 0) ws[w] = s;
    __syncthreads();
    if (t == 0) bsum[b] = ws[0] + ws[1] + ws[2] + ws[3];
}
__global__ void k_scanb(const int* __restrict__ bsum, int* boff, int nb, int* row_ptr, int n) {
    if (threadIdx.x == 0) {
        int acc = 0;
        for (int b = 0; b < nb; b++) { boff[b] = acc; acc += bsum[b]; }
        row_ptr[n] = acc;
    }
}
__global__ void k_scanwrite(const int* __restrict__ deg, const int* __restrict__ boff,
                            int* row_ptr, int* cursor, int n) {
    int b = blockIdx.x, t = threadIdx.x;
    int base = b * 1024 + t * 4;
    int v[4]; int s = 0;
#pragma unroll
    for (int j = 0; j < 4; j++) { int i = base + j; v[j] = (i < n) ? deg[i] - 1 : 0; s += v[j]; }
    int lane = t & 63, w = t >> 6;
    int inc = s;
    for (int d = 1; d < 64; d <<= 1) { int u = __shfl_up(inc, d); if (lane >= d) inc += u; }
    __shared__ int ws[4];
    if (lane == 63) ws[w] = inc;
    __syncthreads();
    int woff = 0;
    for (int i = 0; i < w; i++) woff += ws[i];
    int p = boff[b] + woff + inc - s;
#pragma unroll
    for (int j = 0; j < 4; j++) {
        int i = base + j;
        if (i < n) { row_ptr[i] = p; cursor[i] = p; p += v[j]; }
    }
}
__global__ void k_fill(const int* __restrict__ src, const int* __restrict__ dst,
                       int* cursor, int* col, int e) {
    int i = blockIdx.x * 256 + threadIdx.x;
    if (i < e) {
        int d = dst[i];
        int p = atomicAdd(&cursor[d], 1);
        col[p] = src[i];
    }
}
// transpose weight to Bt layout, converting to bf16 if needed
__global__ void k_transpose_flex(const void* __restrict__ in, u16* __restrict__ out,
                                 int R, int C, const int* __restrict__ flags) {
    int idx = blockIdx.x * 256 + threadIdx.x;
    if (idx >= R * C) return;
    u16 v = flags[0] ? f2bf(((const float*)in)[idx]) : ((const u16*)in)[idx];
    int r = idx / C, c = idx % C;
    out[(size_t)c * R + r] = v;
}

// ---------- MFMA bf16 GEMM, B-transposed input ----------
typedef __bf16 bf16x8 __attribute__((ext_vector_type(8)));
typedef float floatx4 __attribute__((ext_vector_type(4)));

// C[M,Nd] = A[M,Kd] @ Bt[Nd,Kd]^T
// MODE 0: scale row by dinv, store bf16.  MODE 1: plain store at obase (flex dtype).
// AFLEX: A may be fp32 (per flags[0]).   OFLEX: output may be fp32 (per flags[0]).
template <int WROWS, int WCOLS, int TM, int TN, int MODE, bool AFLEX, bool OFLEX>
__global__ __launch_bounds__(256) void k_gemm_bt(const void* __restrict__ A,
                                                 const u16* __restrict__ Bt,
                                                 void* __restrict__ C,
                                                 const float* __restrict__ dinv,
                                                 const int* __restrict__ flags,
                                                 long long obase,
                                                 int M, int Nd, int Kd) {
    constexpr int BM = WROWS * TM * 16;
    constexpr int BN = WCOLS * TN * 16;
    constexpr int BK = 32;
    constexpr int LDP = BK + 8;
    __shared__ u16 As[BM][LDP];
    __shared__ u16 Bs[BN][LDP];
    const int af32 = AFLEX ? flags[0] : 0;
    const int of32 = OFLEX ? flags[0] : 0;
    const int tid = threadIdx.x;
    const int m0 = blockIdx.y * BM;
    const int n0 = blockIdx.x * BN;
    const int lane = tid & 63;
    const int wave = tid >> 6;
    const int wm = wave / WCOLS;
    const int wn = wave % WCOLS;
    const int mrow = lane & 15;
    const int quad = lane >> 4;

    floatx4 acc[TM][TN];
#pragma unroll
    for (int i = 0; i < TM; i++)
#pragma unroll
        for (int j = 0; j < TN; j++) { floatx4 z = {0.f, 0.f, 0.f, 0.f}; acc[i][j] = z; }

    for (int kk = 0; kk < Kd; kk += BK) {
#pragma unroll
        for (int idx = tid * 8; idx < BM * BK; idx += 256 * 8) {
            int r = idx / BK, k = idx % BK;
            int gr = m0 + r;
            if (AFLEX && af32) {
                u16 t8[8] = {0, 0, 0, 0, 0, 0, 0, 0};
                if (gr < M) {
                    const float* ap = (const float*)A + (size_t)gr * Kd + kk + k;
                    float4 f0 = *(const float4*)ap;
                    float4 f1 = *(const float4*)(ap + 4);
                    t8[0] = f2bf(f0.x); t8[1] = f2bf(f0.y); t8[2] = f2bf(f0.z); t8[3] = f2bf(f0.w);
                    t8[4] = f2bf(f1.x); t8[5] = f2bf(f1.y); t8[6] = f2bf(f1.z); t8[7] = f2bf(f1.w);
                }
                *(int4*)&As[r][k] = *(const int4*)t8;
            } else {
                int4 v = {0, 0, 0, 0};
                if (gr < M) v = *(const int4*)((const u16*)A + (size_t)gr * Kd + kk + k);
                *(int4*)&As[r][k] = v;
            }
        }
#pragma unroll
        for (int idx = tid * 8; idx < BN * BK; idx += 256 * 8) {
            int r = idx / BK, k = idx % BK;
            int4 v = {0, 0, 0, 0};
            int gn = n0 + r;
            if (gn < Nd) v = *(const int4*)(Bt + (size_t)gn * Kd + kk + k);
            *(int4*)&Bs[r][k] = v;
        }
        __syncthreads();
        bf16x8 af[TM], bfr[TN];
#pragma unroll
        for (int i = 0; i < TM; i++)
            af[i] = *(const bf16x8*)&As[wm * TM * 16 + i * 16 + mrow][quad * 8];
#pragma unroll
        for (int j = 0; j < TN; j++)
            bfr[j] = *(const bf16x8*)&Bs[wn * TN * 16 + j * 16 + mrow][quad * 8];
#pragma unroll
        for (int i = 0; i < TM; i++)
#pragma unroll
            for (int j = 0; j < TN; j++)
                acc[i][j] = __builtin_amdgcn_mfma_f32_16x16x32_bf16(af[i], bfr[j], acc[i][j], 0, 0, 0);
        __syncthreads();
    }

#pragma unroll
    for (int i = 0; i < TM; i++) {
#pragma unroll
        for (int r = 0; r < 4; r++) {
            int grow = m0 + wm * TM * 16 + i * 16 + quad * 4 + r;
            if (grow < M) {
                float scale = (MODE == 0) ? dinv[grow] : 1.0f;
#pragma unroll
                for (int j = 0; j < TN; j++) {
                    int gcol = n0 + wn * TN * 16 + j * 16 + mrow;
                    float val = acc[i][j][r] * scale;
                    long long cidx = obase + (long long)grow * Nd + gcol;
                    if (OFLEX && of32) ((float*)C)[cidx] = val;
                    else               ((u16*)C)[cidx] = f2bf(val);
                }
            }
        }
    }
}

// ---------- CSR gather-aggregate: one wave per node, H=256 (4 bf16/lane) ----------
__global__ __launch_bounds__(256) void k_agg(const u16* __restrict__ g, u16* __restrict__ out,
                                             const int* __restrict__ row_ptr,
                                             const int* __restrict__ col,
                                             const float* __restrict__ dinv,
                                             const void* __restrict__ bias,
                                             const int* __restrict__ flags,
                                             int n, int do_relu) {
    int wid = (int)((blockIdx.x * 256 + threadIdx.x) >> 6);
    int lane = threadIdx.x & 63;
    if (wid >= n) return;
    int c0 = lane * 4;
    uint2 rv = *(const uint2*)(g + (size_t)wid * 256 + c0);   // self term g[dst]
    float a0 = bfl(rv.x), a1 = bfh(rv.x), a2 = bfl(rv.y), a3 = bfh(rv.y);
    int beg = row_ptr[wid], end = row_ptr[wid + 1];
    for (int j = beg; j < end; ++j) {
        int s = col[j];
        uint2 v = *(const uint2*)(g + (size_t)s * 256 + c0);
        a0 += bfl(v.x); a1 += bfh(v.x); a2 += bfl(v.y); a3 += bfh(v.y);
    }
    float dv = dinv[wid];
    float b0, b1, b2, b3;
    if (flags[0]) {
        float4 q = ((const float4*)bias)[lane];
        b0 = q.x; b1 = q.y; b2 = q.z; b3 = q.w;
    } else {
        uint2 bv = ((const uint2*)bias)[lane];
        b0 = bfl(bv.x); b1 = bfh(bv.x); b2 = bfl(bv.y); b3 = bfh(bv.y);
    }
    a0 = a0 * dv + b0;
    a1 = a1 * dv + b1;
    a2 = a2 * dv + b2;
    a3 = a3 * dv + b3;
    if (do_relu) {
        a0 = fmaxf(a0, 0.f); a1 = fmaxf(a1, 0.f); a2 = fmaxf(a2, 0.f); a3 = fmaxf(a3, 0.f);
    }
    uint2 o;
    o.x = (u32)f2bf(a0) | ((u32)f2bf(a1) << 16);
    o.y = (u32)f2bf(a2) | ((u32)f2bf(a3) << 16);
    *(uint2*)(out + (size_t)wid * 256 + c0) = o;
}

// ---------- softmax over K=64: logits at element offset NK inside d_out ----------
__global__ __launch_bounds__(256) void k_softmax(void* __restrict__ out, long long NK,
                                                 const int* __restrict__ flags, int n) {
    int wid = (int)((blockIdx.x * 256 + threadIdx.x) >> 6);
    int lane = threadIdx.x & 63;
    if (wid >= n) return;
    int f32o = flags[0];
    float lt = ((const float*)flags)[2];
    float inv_tau = __expf(-lt);
    long long li = NK + (long long)wid * 64 + lane;
    float x = f32o ? ((const float*)out)[li] : bf2f(((const u16*)out)[li]);
    x *= inv_tau;
    float m = x;
    for (int d = 32; d; d >>= 1) m = fmaxf(m, __shfl_xor(m, d));
    float e = __expf(x - m);
    float s = e;
    for (int d = 32; d; d >>= 1) s += __shfl_xor(s, d);
    float r = e / s;
    long long si = (long long)wid * 64 + lane;
    if (f32o) ((float*)out)[si] = r;
    else      ((u16*)out)[si] = f2bf(r);
}

extern "C" void kernel_launch(void* const* d_in, const int* in_sizes, int n_in,
                              void* d_out, int out_size, void* d_ws, size_t ws_size,
                              hipStream_t stream) {
    const void* x    = d_in[0];
    const int*  ei   = (const int*)d_in[1];
    const void* W1   = d_in[2];
    const void* b1   = d_in[3];
    const void* W2   = d_in[4];
    const void* b2   = d_in[5];
    const void* Wk   = d_in[6];
    const void* ltau = d_in[7];
    const int D = 512, H = 256, K = 64;
    const int N = in_sizes[0] / D;
    const int E = in_sizes[1] / 2;
    const long long NK = (long long)N * K;

    // ---- workspace: only the two big ping-pong buffers + flags ----
    u16* g = (u16*)d_ws;                      // N*H bf16 = 51.2 MB
    u16* h = g + (size_t)N * H;               // N*H bf16 = 51.2 MB
    int* flags = (int*)(h + (size_t)N * H);   // 256 B
    // src/dst overlay g's space (dead before GEMM1 writes g)
    int* srcv = (int*)g;
    int* dstv = srcv + E;

    // ---- d_out scratch (S-region is dead until the final softmax) ----
    size_t ooff = 0;
    auto oalloc = [&](size_t bytes) -> char* {
        char* p = (char*)d_out + ooff;
        ooff += (bytes + 255) & ~(size_t)255;
        return p;
    };
    int*   col     = (int*)oalloc((size_t)E * 4);
    int*   deg     = (int*)oalloc((size_t)N * 4);
    float* dinv    = (float*)oalloc((size_t)N * 4);
    int*   row_ptr = (int*)oalloc((size_t)(N + 1) * 4);
    int*   cursor  = (int*)oalloc((size_t)N * 4);
    int*   bsum    = (int*)oalloc(1024);
    int*   boff    = (int*)oalloc(1024);
    u16*   W1t     = (u16*)oalloc((size_t)D * H * 2);
    u16*   W2t     = (u16*)oalloc((size_t)H * H * 2);
    u16*   Wkt     = (u16*)oalloc((size_t)H * K * 2);
    // total ≈ 8.5 MB < min(S-region) = N*K*2 bytes = 12.8 MB

    const int nb = (N + 1023) / 1024;
    auto g256 = [](long long n) { return (int)((n + 255) / 256); };

    k_detect<<<1, 256, 0, stream>>>((const u32*)x, ei, ltau, flags, in_sizes[0] / 2, E);
    k_edges<<<g256(E), 256, 0, stream>>>(ei, srcv, dstv, E, flags);
    k_deginit<<<g256(N), 256, 0, stream>>>(deg, N);
    k_degcount<<<g256(E), 256, 0, stream>>>(dstv, deg, E);
    k_dinv<<<g256(N), 256, 0, stream>>>(deg, dinv, N);
    k_blocksum<<<nb, 256, 0, stream>>>(deg, bsum, N);
    k_scanb<<<1, 64, 0, stream>>>(bsum, boff, nb, row_ptr, N);
    k_scanwrite<<<nb, 256, 0, stream>>>(deg, boff, row_ptr, cursor, N);
    k_fill<<<g256(E), 256, 0, stream>>>(srcv, dstv, cursor, col, E);

    k_transpose_flex<<<g256((long long)D * H), 256, 0, stream>>>(W1, W1t, D, H, flags);
    k_transpose_flex<<<g256((long long)H * H), 256, 0, stream>>>(W2, W2t, H, H, flags);
    k_transpose_flex<<<g256((long long)H * K), 256, 0, stream>>>(Wk, Wkt, H, K, flags);

    const int mtiles = (N + 127) / 128;
    // layer 1: g = dinv ⊙ (x @ W1)   (A may be fp32)
    k_gemm_bt<2, 2, 4, 4, 0, true, false>
        <<<dim3(H / 128, mtiles), 256, 0, stream>>>(x, W1t, g, dinv, flags, 0, N, H, D);
    k_agg<<<g256((long long)N * 64), 256, 0, stream>>>(g, h, row_ptr, col, dinv, b1, flags, N, 1);
    // layer 2: g = dinv ⊙ (h @ W2)
    k_gemm_bt<2, 2, 4, 4, 0, false, false>
        <<<dim3(H / 128, mtiles), 256, 0, stream>>>(h, W2t, g, dinv, flags, 0, N, H, H);
    k_agg<<<g256((long long)N * 64), 256, 0, stream>>>(g, h, row_ptr, col, dinv, b2, flags, N, 0);
    // logits = h2 @ Wk  -> d_out second half (dtype per flags)
    k_gemm_bt<4, 1, 2, 4, 1, false, true>
        <<<dim3(1, mtiles), 256, 0, stream>>>(h, Wkt, d_out, dinv, flags, NK, N, K, H);
    // softmax -> d_out first half
    k_softmax<<<g256((long long)N * 64), 256, 0, stream>>>(d_out, NK, flags, N);
}

// Round 3
// 884.103 us; speedup vs baseline: 1.1545x; 1.1545x over previous
//
#include <hip/hip_runtime.h>

typedef unsigned short u16;
typedef unsigned int u32;

// ---------- bf16 helpers (bit-level, RNE) ----------
__device__ __forceinline__ float bfl(u32 u) { union { u32 i; float f; } v; v.i = u << 16; return v.f; }
__device__ __forceinline__ float bfh(u32 u) { union { u32 i; float f; } v; v.i = u & 0xffff0000u; return v.f; }
__device__ __forceinline__ float bf2f(u16 u) { union { u32 i; float f; } v; v.i = ((u32)u) << 16; return v.f; }
__device__ __forceinline__ u16 f2bf(float f) {
    union { float f; u32 i; } v; v.f = f;
    u32 r = v.i + 0x7fffu + ((v.i >> 16) & 1u);
    return (u16)(r >> 16);
}

// ---------- async global->LDS 16B ----------
typedef const __attribute__((address_space(1))) unsigned int* gas_u32;
typedef __attribute__((address_space(3))) unsigned int* las_u32;
__device__ __forceinline__ void async_cp16(const void* g, void* l) {
    __builtin_amdgcn_global_load_lds((gas_u32)g, (las_u32)l, 16, 0, 0);
}

// ---------- dtype detection (device-side, no host sync) ----------
__global__ void k_detect(const u32* __restrict__ xw, const int* __restrict__ eiw,
                         const void* __restrict__ ltau, int* __restrict__ flags,
                         int xwords, int E) {
    __shared__ int cf32, ci64nz;
    if (threadIdx.x == 0) { cf32 = 0; ci64nz = 0; }
    __syncthreads();
    int t = threadIdx.x;             // 256 threads
    int xs = xwords / 256;
    u32 w = xw[(size_t)t * xs];
    int e = (int)((w >> 23) & 0xFFu);
    if (e >= 100 && e <= 140) atomicAdd(&cf32, 1);
    int es = E / 256;
    int hw = eiw[2 * (size_t)t * es + 1];   // odd int32 position
    if (hw != 0) atomicAdd(&ci64nz, 1);
    __syncthreads();
    if (t == 0) {
        int f32 = (cf32 >= 192) ? 1 : 0;
        flags[0] = f32;
        flags[1] = (ci64nz == 0) ? 1 : 0;
        ((float*)flags)[2] = f32 ? ((const float*)ltau)[0] : bf2f(((const u16*)ltau)[0]);
    }
}

// ---------- extract src/dst as int32 regardless of edge width ----------
__global__ void k_edges(const int* __restrict__ ei, int* __restrict__ src, int* __restrict__ dst,
                        int e, const int* __restrict__ flags) {
    int i = blockIdx.x * 256 + threadIdx.x;
    if (i >= e) return;
    if (flags[1]) { src[i] = ei[2 * i]; dst[i] = ei[2 * (e + i)]; }   // int64 low words
    else          { src[i] = ei[i];     dst[i] = ei[e + i]; }
}

// ---------- graph prep ----------
__global__ void k_deginit(int* deg, int n) {
    int i = blockIdx.x * 256 + threadIdx.x;
    if (i < n) deg[i] = 1;           // self-loop
}
__global__ void k_degcount(const int* __restrict__ dst, int* deg, int e) {
    int i = blockIdx.x * 256 + threadIdx.x;
    if (i < e) atomicAdd(&deg[dst[i]], 1);
}
__global__ void k_dinv(const int* __restrict__ deg, float* dinv, int n) {
    int i = blockIdx.x * 256 + threadIdx.x;
    if (i < n) dinv[i] = rsqrtf((float)deg[i]);
}
__global__ void k_blocksum(const int* __restrict__ deg, int* bsum, int n) {
    int b = blockIdx.x, t = threadIdx.x;
    int base = b * 1024 + t * 4;
    int s = 0;
#pragma unroll
    for (int j = 0; j < 4; j++) { int i = base + j; if (i < n) s += deg[i] - 1; }
    for (int d = 32; d; d >>= 1) s += __shfl_down(s, d);
    __shared__ int ws[4];
    int lane = t & 63, w = t >> 6;
    if (lane == 0) ws[w] = s;
    __syncthreads();
    if (t == 0) bsum[b] = ws[0] + ws[1] + ws[2] + ws[3];
}
__global__ void k_scanb(const int* __restrict__ bsum, int* boff, int nb, int* row_ptr, int n) {
    if (threadIdx.x == 0) {
        int acc = 0;
        for (int b = 0; b < nb; b++) { boff[b] = acc; acc += bsum[b]; }
        row_ptr[n] = acc;
    }
}
__global__ void k_scanwrite(const int* __restrict__ deg, const int* __restrict__ boff,
                            int* row_ptr, int* cursor, int n) {
    int b = blockIdx.x, t = threadIdx.x;
    int base = b * 1024 + t * 4;
    int v[4]; int s = 0;
#pragma unroll
    for (int j = 0; j < 4; j++) { int i = base + j; v[j] = (i < n) ? deg[i] - 1 : 0; s += v[j]; }
    int lane = t & 63, w = t >> 6;
    int inc = s;
    for (int d = 1; d < 64; d <<= 1) { int u = __shfl_up(inc, d); if (lane >= d) inc += u; }
    __shared__ int ws[4];
    if (lane == 63) ws[w] = inc;
    __syncthreads();
    int woff = 0;
    for (int i = 0; i < w; i++) woff += ws[i];
    int p = boff[b] + woff + inc - s;
#pragma unroll
    for (int j = 0; j < 4; j++) {
        int i = base + j;
        if (i < n) { row_ptr[i] = p; cursor[i] = p; p += v[j]; }
    }
}
__global__ void k_fill(const int* __restrict__ src, const int* __restrict__ dst,
                       int* cursor, int* col, int e) {
    int i = blockIdx.x * 256 + threadIdx.x;
    if (i < e) {
        int d = dst[i];
        int p = atomicAdd(&cursor[d], 1);
        col[p] = src[i];
    }
}
// transpose weight to Bt layout, converting to bf16 if needed
__global__ void k_transpose_flex(const void* __restrict__ in, u16* __restrict__ out,
                                 int R, int C, const int* __restrict__ flags) {
    int idx = blockIdx.x * 256 + threadIdx.x;
    if (idx >= R * C) return;
    u16 v = flags[0] ? f2bf(((const float*)in)[idx]) : ((const u16*)in)[idx];
    int r = idx / C, c = idx % C;
    out[(size_t)c * R + r] = v;
}

// ---------- MFMA bf16 GEMM, B-transposed input ----------
typedef __bf16 bf16x8 __attribute__((ext_vector_type(8)));
typedef float floatx4 __attribute__((ext_vector_type(4)));

// C[M,Nd] = A[M,Kd] @ Bt[Nd,Kd]^T
// MODE 0: scale row by dinv, store bf16.  MODE 1: plain store at obase (flex dtype).
// AFLEX: A may be fp32 (per flags[0]).   OFLEX: output may be fp32 (per flags[0]).
// bf16 path stages via global_load_lds width=16 -> LDS UNPADDED (wave-uniform rule).
template <int WROWS, int WCOLS, int TM, int TN, int MODE, bool AFLEX, bool OFLEX>
__global__ __launch_bounds__(256) void k_gemm_bt(const void* __restrict__ A,
                                                 const u16* __restrict__ Bt,
                                                 void* __restrict__ C,
                                                 const float* __restrict__ dinv,
                                                 const int* __restrict__ flags,
                                                 long long obase,
                                                 int M, int Nd, int Kd) {
    constexpr int BM = WROWS * TM * 16;
    constexpr int BN = WCOLS * TN * 16;
    constexpr int BK = 32;
    __shared__ u16 As[BM][BK];
    __shared__ u16 Bs[BN][BK];
    const int af32 = AFLEX ? flags[0] : 0;
    const int of32 = OFLEX ? flags[0] : 0;
    const int tid = threadIdx.x;
    const int m0 = blockIdx.y * BM;
    const int n0 = blockIdx.x * BN;
    const int lane = tid & 63;
    const int wave = tid >> 6;
    const int wm = wave / WCOLS;
    const int wn = wave % WCOLS;
    const int mrow = lane & 15;
    const int quad = lane >> 4;

    floatx4 acc[TM][TN];
#pragma unroll
    for (int i = 0; i < TM; i++)
#pragma unroll
        for (int j = 0; j < TN; j++) { floatx4 z = {0.f, 0.f, 0.f, 0.f}; acc[i][j] = z; }

    for (int kk = 0; kk < Kd; kk += BK) {
        if (AFLEX && af32) {
#pragma unroll
            for (int idx = tid * 8; idx < BM * BK; idx += 256 * 8) {
                int r = idx >> 5, k = idx & 31;
                int gr = m0 + r;
                u16 t8[8] = {0, 0, 0, 0, 0, 0, 0, 0};
                if (gr < M) {
                    const float* ap = (const float*)A + (size_t)gr * Kd + kk + k;
                    float4 f0 = *(const float4*)ap;
                    float4 f1 = *(const float4*)(ap + 4);
                    t8[0] = f2bf(f0.x); t8[1] = f2bf(f0.y); t8[2] = f2bf(f0.z); t8[3] = f2bf(f0.w);
                    t8[4] = f2bf(f1.x); t8[5] = f2bf(f1.y); t8[6] = f2bf(f1.z); t8[7] = f2bf(f1.w);
                }
                *(int4*)&As[r][k] = *(const int4*)t8;
            }
        } else {
#pragma unroll
            for (int idx = tid * 8; idx < BM * BK; idx += 256 * 8) {
                int r = idx >> 5, k = idx & 31;
                int gr = m0 + r;
                if (gr >= M) gr = M - 1;   // clamp: garbage only reaches discarded OOB C-rows
                async_cp16((const u16*)A + (size_t)gr * Kd + kk + k, &As[r][k]);
            }
        }
#pragma unroll
        for (int idx = tid * 8; idx < BN * BK; idx += 256 * 8) {
            int r = idx >> 5, k = idx & 31;
            async_cp16(Bt + (size_t)(n0 + r) * Kd + kk + k, &Bs[r][k]);
        }
        __syncthreads();
        bf16x8 af[TM], bfr[TN];
#pragma unroll
        for (int i = 0; i < TM; i++)
            af[i] = *(const bf16x8*)&As[wm * TM * 16 + i * 16 + mrow][quad * 8];
#pragma unroll
        for (int j = 0; j < TN; j++)
            bfr[j] = *(const bf16x8*)&Bs[wn * TN * 16 + j * 16 + mrow][quad * 8];
#pragma unroll
        for (int i = 0; i < TM; i++)
#pragma unroll
            for (int j = 0; j < TN; j++)
                acc[i][j] = __builtin_amdgcn_mfma_f32_16x16x32_bf16(af[i], bfr[j], acc[i][j], 0, 0, 0);
        __syncthreads();
    }

#pragma unroll
    for (int i = 0; i < TM; i++) {
#pragma unroll
        for (int r = 0; r < 4; r++) {
            int grow = m0 + wm * TM * 16 + i * 16 + quad * 4 + r;
            if (grow < M) {
                float scale = (MODE == 0) ? dinv[grow] : 1.0f;
#pragma unroll
                for (int j = 0; j < TN; j++) {
                    int gcol = n0 + wn * TN * 16 + j * 16 + mrow;
                    float val = acc[i][j][r] * scale;
                    long long cidx = obase + (long long)grow * Nd + gcol;
                    if (OFLEX && of32) ((float*)C)[cidx] = val;
                    else               ((u16*)C)[cidx] = f2bf(val);
                }
            }
        }
    }
}

// ---------- CSR gather-aggregate: one wave per node, H=256 (4 bf16/lane) ----------
// v2: lane-parallel col preload + shfl broadcast + 4-wide independent gather batches
__global__ __launch_bounds__(256) void k_agg(const u16* __restrict__ g, u16* __restrict__ out,
                                             const int* __restrict__ row_ptr,
                                             const int* __restrict__ col,
                                             const float* __restrict__ dinv,
                                             const void* __restrict__ bias,
                                             const int* __restrict__ flags,
                                             int n, int do_relu) {
    int wid = (int)((blockIdx.x * 256 + threadIdx.x) >> 6);
    int lane = threadIdx.x & 63;
    if (wid >= n) return;
    const u16* gp = g + (size_t)lane * 4;
    uint2 rv = *(const uint2*)(gp + (size_t)wid * 256);   // self term g[dst]
    float a0 = bfl(rv.x), a1 = bfh(rv.x), a2 = bfl(rv.y), a3 = bfh(rv.y);
    int beg = row_ptr[wid], end = row_ptr[wid + 1];
    for (int base = beg; base < end; base += 64) {
        int m = end - base; if (m > 64) m = 64;
        int ci = (base + lane < end) ? col[base + lane] : 0;   // 1 coalesced load / chunk
        int j = 0;
        for (; j + 4 <= m; j += 4) {
            int s0 = __shfl(ci, j);
            int s1 = __shfl(ci, j + 1);
            int s2 = __shfl(ci, j + 2);
            int s3 = __shfl(ci, j + 3);
            uint2 v0 = *(const uint2*)(gp + (size_t)s0 * 256);
            uint2 v1 = *(const uint2*)(gp + (size_t)s1 * 256);
            uint2 v2 = *(const uint2*)(gp + (size_t)s2 * 256);
            uint2 v3 = *(const uint2*)(gp + (size_t)s3 * 256);
            a0 += bfl(v0.x) + bfl(v1.x) + bfl(v2.x) + bfl(v3.x);
            a1 += bfh(v0.x) + bfh(v1.x) + bfh(v2.x) + bfh(v3.x);
            a2 += bfl(v0.y) + bfl(v1.y) + bfl(v2.y) + bfl(v3.y);
            a3 += bfh(v0.y) + bfh(v1.y) + bfh(v2.y) + bfh(v3.y);
        }
        for (; j < m; j++) {
            int s = __shfl(ci, j);
            uint2 v = *(const uint2*)(gp + (size_t)s * 256);
            a0 += bfl(v.x); a1 += bfh(v.x); a2 += bfl(v.y); a3 += bfh(v.y);
        }
    }
    float dv = dinv[wid];
    float b0, b1, b2, b3;
    if (flags[0]) {
        float4 q = ((const float4*)bias)[lane];
        b0 = q.x; b1 = q.y; b2 = q.z; b3 = q.w;
    } else {
        uint2 bv = ((const uint2*)bias)[lane];
        b0 = bfl(bv.x); b1 = bfh(bv.x); b2 = bfl(bv.y); b3 = bfh(bv.y);
    }
    a0 = a0 * dv + b0;
    a1 = a1 * dv + b1;
    a2 = a2 * dv + b2;
    a3 = a3 * dv + b3;
    if (do_relu) {
        a0 = fmaxf(a0, 0.f); a1 = fmaxf(a1, 0.f); a2 = fmaxf(a2, 0.f); a3 = fmaxf(a3, 0.f);
    }
    uint2 o;
    o.x = (u32)f2bf(a0) | ((u32)f2bf(a1) << 16);
    o.y = (u32)f2bf(a2) | ((u32)f2bf(a3) << 16);
    *(uint2*)(out + (size_t)wid * 256 + (size_t)lane * 4) = o;
}

// ---------- softmax over K=64: logits at element offset NK inside d_out ----------
__global__ __launch_bounds__(256) void k_softmax(void* __restrict__ out, long long NK,
                                                 const int* __restrict__ flags, int n) {
    int wid = (int)((blockIdx.x * 256 + threadIdx.x) >> 6);
    int lane = threadIdx.x & 63;
    if (wid >= n) return;
    int f32o = flags[0];
    float lt = ((const float*)flags)[2];
    float inv_tau = __expf(-lt);
    long long li = NK + (long long)wid * 64 + lane;
    float x = f32o ? ((const float*)out)[li] : bf2f(((const u16*)out)[li]);
    x *= inv_tau;
    float m = x;
    for (int d = 32; d; d >>= 1) m = fmaxf(m, __shfl_xor(m, d));
    float e = __expf(x - m);
    float s = e;
    for (int d = 32; d; d >>= 1) s += __shfl_xor(s, d);
    float r = e / s;
    long long si = (long long)wid * 64 + lane;
    if (f32o) ((float*)out)[si] = r;
    else      ((u16*)out)[si] = f2bf(r);
}

extern "C" void kernel_launch(void* const* d_in, const int* in_sizes, int n_in,
                              void* d_out, int out_size, void* d_ws, size_t ws_size,
                              hipStream_t stream) {
    const void* x    = d_in[0];
    const int*  ei   = (const int*)d_in[1];
    const void* W1   = d_in[2];
    const void* b1   = d_in[3];
    const void* W2   = d_in[4];
    const void* b2   = d_in[5];
    const void* Wk   = d_in[6];
    const void* ltau = d_in[7];
    const int D = 512, H = 256, K = 64;
    const int N = in_sizes[0] / D;
    const int E = in_sizes[1] / 2;
    const long long NK = (long long)N * K;

    // ---- workspace: only the two big ping-pong buffers + flags ----
    u16* g = (u16*)d_ws;                      // N*H bf16 = 51.2 MB
    u16* h = g + (size_t)N * H;               // N*H bf16 = 51.2 MB
    int* flags = (int*)(h + (size_t)N * H);   // 256 B
    // src/dst overlay g's space (dead before GEMM1 writes g)
    int* srcv = (int*)g;
    int* dstv = srcv + E;

    // ---- d_out scratch (S-region is dead until the final softmax) ----
    size_t ooff = 0;
    auto oalloc = [&](size_t bytes) -> char* {
        char* p = (char*)d_out + ooff;
        ooff += (bytes + 255) & ~(size_t)255;
        return p;
    };
    int*   col     = (int*)oalloc((size_t)E * 4);
    int*   deg     = (int*)oalloc((size_t)N * 4);
    float* dinv    = (float*)oalloc((size_t)N * 4);
    int*   row_ptr = (int*)oalloc((size_t)(N + 1) * 4);
    int*   cursor  = (int*)oalloc((size_t)N * 4);
    int*   bsum    = (int*)oalloc(1024);
    int*   boff    = (int*)oalloc(1024);
    u16*   W1t     = (u16*)oalloc((size_t)D * H * 2);
    u16*   W2t     = (u16*)oalloc((size_t)H * H * 2);
    u16*   Wkt     = (u16*)oalloc((size_t)H * K * 2);
    // total ≈ 8.5 MB < min(S-region) = N*K*2 bytes = 12.8 MB

    const int nb = (N + 1023) / 1024;
    auto g256 = [](long long n) { return (int)((n + 255) / 256); };

    k_detect<<<1, 256, 0, stream>>>((const u32*)x, ei, ltau, flags, in_sizes[0] / 2, E);
    k_edges<<<g256(E), 256, 0, stream>>>(ei, srcv, dstv, E, flags);
    k_deginit<<<g256(N), 256, 0, stream>>>(deg, N);
    k_degcount<<<g256(E), 256, 0, stream>>>(dstv, deg, E);
    k_dinv<<<g256(N), 256, 0, stream>>>(deg, dinv, N);
    k_blocksum<<<nb, 256, 0, stream>>>(deg, bsum, N);
    k_scanb<<<1, 64, 0, stream>>>(bsum, boff, nb, row_ptr, N);
    k_scanwrite<<<nb, 256, 0, stream>>>(deg, boff, row_ptr, cursor, N);
    k_fill<<<g256(E), 256, 0, stream>>>(srcv, dstv, cursor, col, E);

    k_transpose_flex<<<g256((long long)D * H), 256, 0, stream>>>(W1, W1t, D, H, flags);
    k_transpose_flex<<<g256((long long)H * H), 256, 0, stream>>>(W2, W2t, H, H, flags);
    k_transpose_flex<<<g256((long long)H * K), 256, 0, stream>>>(Wk, Wkt, H, K, flags);

    const int mtiles = (N + 127) / 128;
    // layer 1: g = dinv ⊙ (x @ W1)   (A may be fp32)
    k_gemm_bt<2, 2, 4, 4, 0, true, false>
        <<<dim3(H / 128, mtiles), 256, 0, stream>>>(x, W1t, g, dinv, flags, 0, N, H, D);
    k_agg<<<g256((long long)N * 64), 256, 0, stream>>>(g, h, row_ptr, col, dinv, b1, flags, N, 1);
    // layer 2: g = dinv ⊙ (h @ W2)
    k_gemm_bt<2, 2, 4, 4, 0, false, false>
        <<<dim3(H / 128, mtiles), 256, 0, stream>>>(h, W2t, g, dinv, flags, 0, N, H, H);
    k_agg<<<g256((long long)N * 64), 256, 0, stream>>>(g, h, row_ptr, col, dinv, b2, flags, N, 0);
    // logits = h2 @ Wk  -> d_out second half (dtype per flags)
    k_gemm_bt<4, 1, 2, 4, 1, false, true>
        <<<dim3(1, mtiles), 256, 0, stream>>>(h, Wkt, d_out, dinv, flags, NK, N, K, H);
    // softmax -> d_out first half
    k_softmax<<<g256((long long)N * 64), 256, 0, stream>>>(d_out, NK, flags, N);
}

// Round 4
// 870.371 us; speedup vs baseline: 1.1727x; 1.0158x over previous
//
#include <hip/hip_runtime.h>

typedef unsigned short u16;
typedef unsigned int u32;

// ---------- bf16 helpers (bit-level, RNE) ----------
__device__ __forceinline__ float bfl(u32 u) { union { u32 i; float f; } v; v.i = u << 16; return v.f; }
__device__ __forceinline__ float bfh(u32 u) { union { u32 i; float f; } v; v.i = u & 0xffff0000u; return v.f; }
__device__ __forceinline__ float bf2f(u16 u) { union { u32 i; float f; } v; v.i = ((u32)u) << 16; return v.f; }
__device__ __forceinline__ u16 f2bf(float f) {
    union { float f; u32 i; } v; v.f = f;
    u32 r = v.i + 0x7fffu + ((v.i >> 16) & 1u);
    return (u16)(r >> 16);
}

// ---------- async global->LDS 16B ----------
typedef const __attribute__((address_space(1))) unsigned int* gas_u32;
typedef __attribute__((address_space(3))) unsigned int* las_u32;
__device__ __forceinline__ void async_cp16(const void* g, void* l) {
    __builtin_amdgcn_global_load_lds((gas_u32)g, (las_u32)l, 16, 0, 0);
}

// ---------- dtype detection (device-side, no host sync) ----------
__global__ void k_detect(const u32* __restrict__ xw, const int* __restrict__ eiw,
                         const void* __restrict__ ltau, int* __restrict__ flags,
                         int xwords, int E) {
    __shared__ int cf32, ci64nz;
    if (threadIdx.x == 0) { cf32 = 0; ci64nz = 0; }
    __syncthreads();
    int t = threadIdx.x;             // 256 threads
    int xs = xwords / 256;
    u32 w = xw[(size_t)t * xs];
    int e = (int)((w >> 23) & 0xFFu);
    if (e >= 100 && e <= 140) atomicAdd(&cf32, 1);
    int es = E / 256;
    int hw = eiw[2 * (size_t)t * es + 1];   // odd int32 position
    if (hw != 0) atomicAdd(&ci64nz, 1);
    __syncthreads();
    if (t == 0) {
        int f32 = (cf32 >= 192) ? 1 : 0;
        flags[0] = f32;
        flags[1] = (ci64nz == 0) ? 1 : 0;
        ((float*)flags)[2] = f32 ? ((const float*)ltau)[0] : bf2f(((const u16*)ltau)[0]);
    }
}

// ---------- extract src/dst as int32 regardless of edge width ----------
__global__ void k_edges(const int* __restrict__ ei, int* __restrict__ src, int* __restrict__ dst,
                        int e, const int* __restrict__ flags) {
    int i = blockIdx.x * 256 + threadIdx.x;
    if (i >= e) return;
    if (flags[1]) { src[i] = ei[2 * i]; dst[i] = ei[2 * (e + i)]; }   // int64 low words
    else          { src[i] = ei[i];     dst[i] = ei[e + i]; }
}

// ---------- graph prep ----------
__global__ void k_deginit(int* deg, int n) {
    int i = blockIdx.x * 256 + threadIdx.x;
    if (i < n) deg[i] = 1;           // self-loop
}
__global__ void k_degcount(const int* __restrict__ dst, int* deg, int e) {
    int i = blockIdx.x * 256 + threadIdx.x;
    if (i < e) atomicAdd(&deg[dst[i]], 1);
}
__global__ void k_dinv(const int* __restrict__ deg, float* dinv, int n) {
    int i = blockIdx.x * 256 + threadIdx.x;
    if (i < n) dinv[i] = rsqrtf((float)deg[i]);
}
__global__ void k_blocksum(const int* __restrict__ deg, int* bsum, int n) {
    int b = blockIdx.x, t = threadIdx.x;
    int base = b * 1024 + t * 4;
    int s = 0;
#pragma unroll
    for (int j = 0; j < 4; j++) { int i = base + j; if (i < n) s += deg[i] - 1; }
    for (int d = 32; d; d >>= 1) s += __shfl_down(s, d);
    __shared__ int ws[4];
    int lane = t & 63, w = t >> 6;
    if (lane == 0) ws[w] = s;
    __syncthreads();
    if (t == 0) bsum[b] = ws[0] + ws[1] + ws[2] + ws[3];
}
__global__ void k_scanb(const int* __restrict__ bsum, int* boff, int nb, int* row_ptr, int n) {
    if (threadIdx.x == 0) {
        int acc = 0;
        for (int b = 0; b < nb; b++) { boff[b] = acc; acc += bsum[b]; }
        row_ptr[n] = acc;
    }
}
__global__ void k_scanwrite(const int* __restrict__ deg, const int* __restrict__ boff,
                            int* row_ptr, int* cursor, int n) {
    int b = blockIdx.x, t = threadIdx.x;
    int base = b * 1024 + t * 4;
    int v[4]; int s = 0;
#pragma unroll
    for (int j = 0; j < 4; j++) { int i = base + j; v[j] = (i < n) ? deg[i] - 1 : 0; s += v[j]; }
    int lane = t & 63, w = t >> 6;
    int inc = s;
    for (int d = 1; d < 64; d <<= 1) { int u = __shfl_up(inc, d); if (lane >= d) inc += u; }
    __shared__ int ws[4];
    if (lane == 63) ws[w] = inc;
    __syncthreads();
    int woff = 0;
    for (int i = 0; i < w; i++) woff += ws[i];
    int p = boff[b] + woff + inc - s;
#pragma unroll
    for (int j = 0; j < 4; j++) {
        int i = base + j;
        if (i < n) { row_ptr[i] = p; cursor[i] = p; p += v[j]; }
    }
}
__global__ void k_fill(const int* __restrict__ src, const int* __restrict__ dst,
                       int* cursor, int* col, int e) {
    int i = blockIdx.x * 256 + threadIdx.x;
    if (i < e) {
        int d = dst[i];
        int p = atomicAdd(&cursor[d], 1);
        col[p] = src[i];
    }
}
// transpose weight to Bt layout, converting to bf16 if needed
__global__ void k_transpose_flex(const void* __restrict__ in, u16* __restrict__ out,
                                 int R, int C, const int* __restrict__ flags) {
    int idx = blockIdx.x * 256 + threadIdx.x;
    if (idx >= R * C) return;
    u16 v = flags[0] ? f2bf(((const float*)in)[idx]) : ((const u16*)in)[idx];
    int r = idx / C, c = idx % C;
    out[(size_t)c * R + r] = v;
}

// ---------- MFMA bf16 GEMM, B-transposed input, double-buffered LDS ----------
typedef __bf16 bf16x8 __attribute__((ext_vector_type(8)));
typedef float floatx4 __attribute__((ext_vector_type(4)));

// C[M,Nd] = A[M,Kd] @ Bt[Nd,Kd]^T
// MODE 0: scale row by dinv, store bf16.  MODE 1: plain store at obase (flex dtype).
// AFLEX: A may be fp32 (per flags[0]).   OFLEX: output may be fp32 (per flags[0]).
// bf16 path stages via global_load_lds width=16 -> LDS UNPADDED (wave-uniform rule).
// Pipeline: barrier drains stage(s); stage(s+1) issued BEFORE compute(s) so the
// global->LDS latency overlaps ds_read+MFMA (no vmcnt dependency in compute).
template <int WROWS, int WCOLS, int TM, int TN, int MODE, bool AFLEX, bool OFLEX>
__global__ __launch_bounds__(256, 2) void k_gemm_bt(const void* __restrict__ A,
                                                    const u16* __restrict__ Bt,
                                                    void* __restrict__ C,
                                                    const float* __restrict__ dinv,
                                                    const int* __restrict__ flags,
                                                    long long obase,
                                                    int M, int Nd, int Kd) {
    constexpr int BM = WROWS * TM * 16;
    constexpr int BN = WCOLS * TN * 16;
    constexpr int BK = 32;
    __shared__ u16 As[2][BM][BK];
    __shared__ u16 Bs[2][BN][BK];
    const int af32 = AFLEX ? flags[0] : 0;
    const int of32 = OFLEX ? flags[0] : 0;
    const int tid = threadIdx.x;
    const int m0 = blockIdx.y * BM;
    const int n0 = blockIdx.x * BN;
    const int lane = tid & 63;
    const int wave = tid >> 6;
    const int wm = wave / WCOLS;
    const int wn = wave % WCOLS;
    const int mrow = lane & 15;
    const int quad = lane >> 4;

    floatx4 acc[TM][TN];
#pragma unroll
    for (int i = 0; i < TM; i++)
#pragma unroll
        for (int j = 0; j < TN; j++) { floatx4 z = {0.f, 0.f, 0.f, 0.f}; acc[i][j] = z; }

    auto stage = [&](int kk, int buf) {
        if (AFLEX && af32) {
#pragma unroll
            for (int idx = tid * 8; idx < BM * BK; idx += 256 * 8) {
                int r = idx >> 5, k = idx & 31;
                int gr = m0 + r;
                u16 t8[8] = {0, 0, 0, 0, 0, 0, 0, 0};
                if (gr < M) {
                    const float* ap = (const float*)A + (size_t)gr * Kd + kk + k;
                    float4 f0 = *(const float4*)ap;
                    float4 f1 = *(const float4*)(ap + 4);
                    t8[0] = f2bf(f0.x); t8[1] = f2bf(f0.y); t8[2] = f2bf(f0.z); t8[3] = f2bf(f0.w);
                    t8[4] = f2bf(f1.x); t8[5] = f2bf(f1.y); t8[6] = f2bf(f1.z); t8[7] = f2bf(f1.w);
                }
                *(int4*)&As[buf][r][k] = *(const int4*)t8;
            }
#pragma unroll
            for (int idx = tid * 8; idx < BN * BK; idx += 256 * 8) {
                int r = idx >> 5, k = idx & 31;
                int4 v = *(const int4*)(Bt + (size_t)(n0 + r) * Kd + kk + k);
                *(int4*)&Bs[buf][r][k] = v;
            }
        } else {
#pragma unroll
            for (int idx = tid * 8; idx < BM * BK; idx += 256 * 8) {
                int r = idx >> 5, k = idx & 31;
                int gr = m0 + r;
                if (gr >= M) gr = M - 1;   // clamp: garbage only reaches discarded OOB C-rows
                async_cp16((const u16*)A + (size_t)gr * Kd + kk + k, &As[buf][r][k]);
            }
#pragma unroll
            for (int idx = tid * 8; idx < BN * BK; idx += 256 * 8) {
                int r = idx >> 5, k = idx & 31;
                async_cp16(Bt + (size_t)(n0 + r) * Kd + kk + k, &Bs[buf][r][k]);
            }
        }
    };

    const int steps = Kd / BK;
    stage(0, 0);
    for (int s = 0; s < steps; s++) {
        __syncthreads();                       // drains stage(s)
        if (s + 1 < steps) stage((s + 1) * BK, (s + 1) & 1);   // overlaps compute below
        const int b = s & 1;
        bf16x8 af[TM], bfr[TN];
#pragma unroll
        for (int i = 0; i < TM; i++)
            af[i] = *(const bf16x8*)&As[b][wm * TM * 16 + i * 16 + mrow][quad * 8];
#pragma unroll
        for (int j = 0; j < TN; j++)
            bfr[j] = *(const bf16x8*)&Bs[b][wn * TN * 16 + j * 16 + mrow][quad * 8];
#pragma unroll
        for (int i = 0; i < TM; i++)
#pragma unroll
            for (int j = 0; j < TN; j++)
                acc[i][j] = __builtin_amdgcn_mfma_f32_16x16x32_bf16(af[i], bfr[j], acc[i][j], 0, 0, 0);
    }

#pragma unroll
    for (int i = 0; i < TM; i++) {
#pragma unroll
        for (int r = 0; r < 4; r++) {
            int grow = m0 + wm * TM * 16 + i * 16 + quad * 4 + r;
            if (grow < M) {
                float scale = (MODE == 0) ? dinv[grow] : 1.0f;
#pragma unroll
                for (int j = 0; j < TN; j++) {
                    int gcol = n0 + wn * TN * 16 + j * 16 + mrow;
                    float val = acc[i][j][r] * scale;
                    long long cidx = obase + (long long)grow * Nd + gcol;
                    if (OFLEX && of32) ((float*)C)[cidx] = val;
                    else               ((u16*)C)[cidx] = f2bf(val);
                }
            }
        }
    }
}

// ---------- CSR gather-aggregate: one wave per node, H=256 (4 bf16/lane) ----------
// v3: lane-parallel col preload + shfl broadcast + 8-wide independent gather batches
__global__ __launch_bounds__(256) void k_agg(const u16* __restrict__ g, u16* __restrict__ out,
                                             const int* __restrict__ row_ptr,
                                             const int* __restrict__ col,
                                             const float* __restrict__ dinv,
                                             const void* __restrict__ bias,
                                             const int* __restrict__ flags,
                                             int n, int do_relu) {
    int wid = (int)((blockIdx.x * 256 + threadIdx.x) >> 6);
    int lane = threadIdx.x & 63;
    if (wid >= n) return;
    const u16* gp = g + (size_t)lane * 4;
    uint2 rv = *(const uint2*)(gp + (size_t)wid * 256);   // self term g[dst]
    float a0 = bfl(rv.x), a1 = bfh(rv.x), a2 = bfl(rv.y), a3 = bfh(rv.y);
    int beg = row_ptr[wid], end = row_ptr[wid + 1];
    for (int base = beg; base < end; base += 64) {
        int m = end - base; if (m > 64) m = 64;
        int ci = (base + lane < end) ? col[base + lane] : 0;   // 1 coalesced load / chunk
        int j = 0;
        for (; j + 8 <= m; j += 8) {
            uint2 v[8];
#pragma unroll
            for (int q = 0; q < 8; q++) {
                int s = __shfl(ci, j + q);
                v[q] = *(const uint2*)(gp + (size_t)s * 256);
            }
#pragma unroll
            for (int q = 0; q < 8; q++) {
                a0 += bfl(v[q].x); a1 += bfh(v[q].x);
                a2 += bfl(v[q].y); a3 += bfh(v[q].y);
            }
        }
        for (; j < m; j++) {
            int s = __shfl(ci, j);
            uint2 v = *(const uint2*)(gp + (size_t)s * 256);
            a0 += bfl(v.x); a1 += bfh(v.x); a2 += bfl(v.y); a3 += bfh(v.y);
        }
    }
    float dv = dinv[wid];
    float b0, b1, b2, b3;
    if (flags[0]) {
        float4 q = ((const float4*)bias)[lane];
        b0 = q.x; b1 = q.y; b2 = q.z; b3 = q.w;
    } else {
        uint2 bv = ((const uint2*)bias)[lane];
        b0 = bfl(bv.x); b1 = bfh(bv.x); b2 = bfl(bv.y); b3 = bfh(bv.y);
    }
    a0 = a0 * dv + b0;
    a1 = a1 * dv + b1;
    a2 = a2 * dv + b2;
    a3 = a3 * dv + b3;
    if (do_relu) {
        a0 = fmaxf(a0, 0.f); a1 = fmaxf(a1, 0.f); a2 = fmaxf(a2, 0.f); a3 = fmaxf(a3, 0.f);
    }
    uint2 o;
    o.x = (u32)f2bf(a0) | ((u32)f2bf(a1) << 16);
    o.y = (u32)f2bf(a2) | ((u32)f2bf(a3) << 16);
    *(uint2*)(out + (size_t)wid * 256 + (size_t)lane * 4) = o;
}

// ---------- softmax over K=64: logits at element offset NK inside d_out ----------
__global__ __launch_bounds__(256) void k_softmax(void* __restrict__ out, long long NK,
                                                 const int* __restrict__ flags, int n) {
    int wid = (int)((blockIdx.x * 256 + threadIdx.x) >> 6);
    int lane = threadIdx.x & 63;
    if (wid >= n) return;
    int f32o = flags[0];
    float lt = ((const float*)flags)[2];
    float inv_tau = __expf(-lt);
    long long li = NK + (long long)wid * 64 + lane;
    float x = f32o ? ((const float*)out)[li] : bf2f(((const u16*)out)[li]);
    x *= inv_tau;
    float m = x;
    for (int d = 32; d; d >>= 1) m = fmaxf(m, __shfl_xor(m, d));
    float e = __expf(x - m);
    float s = e;
    for (int d = 32; d; d >>= 1) s += __shfl_xor(s, d);
    float r = e / s;
    long long si = (long long)wid * 64 + lane;
    if (f32o) ((float*)out)[si] = r;
    else      ((u16*)out)[si] = f2bf(r);
}

extern "C" void kernel_launch(void* const* d_in, const int* in_sizes, int n_in,
                              void* d_out, int out_size, void* d_ws, size_t ws_size,
                              hipStream_t stream) {
    const void* x    = d_in[0];
    const int*  ei   = (const int*)d_in[1];
    const void* W1   = d_in[2];
    const void* b1   = d_in[3];
    const void* W2   = d_in[4];
    const void* b2   = d_in[5];
    const void* Wk   = d_in[6];
    const void* ltau = d_in[7];
    const int D = 512, H = 256, K = 64;
    const int N = in_sizes[0] / D;
    const int E = in_sizes[1] / 2;
    const long long NK = (long long)N * K;

    // ---- workspace: only the two big ping-pong buffers + flags ----
    u16* g = (u16*)d_ws;                      // N*H bf16 = 51.2 MB
    u16* h = g + (size_t)N * H;               // N*H bf16 = 51.2 MB
    int* flags = (int*)(h + (size_t)N * H);   // 256 B
    // src/dst overlay g's space (dead before GEMM1 writes g)
    int* srcv = (int*)g;
    int* dstv = srcv + E;

    // ---- d_out scratch (S-region is dead until the final softmax) ----
    size_t ooff = 0;
    auto oalloc = [&](size_t bytes) -> char* {
        char* p = (char*)d_out + ooff;
        ooff += (bytes + 255) & ~(size_t)255;
        return p;
    };
    int*   col     = (int*)oalloc((size_t)E * 4);
    int*   deg     = (int*)oalloc((size_t)N * 4);
    float* dinv    = (float*)oalloc((size_t)N * 4);
    int*   row_ptr = (int*)oalloc((size_t)(N + 1) * 4);
    int*   cursor  = (int*)oalloc((size_t)N * 4);
    int*   bsum    = (int*)oalloc(1024);
    int*   boff    = (int*)oalloc(1024);
    u16*   W1t     = (u16*)oalloc((size_t)D * H * 2);
    u16*   W2t     = (u16*)oalloc((size_t)H * H * 2);
    u16*   Wkt     = (u16*)oalloc((size_t)H * K * 2);
    // total ≈ 8.5 MB < min(S-region) = N*K*2 bytes = 12.8 MB

    const int nb = (N + 1023) / 1024;
    auto g256 = [](long long n) { return (int)((n + 255) / 256); };

    k_detect<<<1, 256, 0, stream>>>((const u32*)x, ei, ltau, flags, in_sizes[0] / 2, E);
    k_edges<<<g256(E), 256, 0, stream>>>(ei, srcv, dstv, E, flags);
    k_deginit<<<g256(N), 256, 0, stream>>>(deg, N);
    k_degcount<<<g256(E), 256, 0, stream>>>(dstv, deg, E);
    k_dinv<<<g256(N), 256, 0, stream>>>(deg, dinv, N);
    k_blocksum<<<nb, 256, 0, stream>>>(deg, bsum, N);
    k_scanb<<<1, 64, 0, stream>>>(bsum, boff, nb, row_ptr, N);
    k_scanwrite<<<nb, 256, 0, stream>>>(deg, boff, row_ptr, cursor, N);
    k_fill<<<g256(E), 256, 0, stream>>>(srcv, dstv, cursor, col, E);

    k_transpose_flex<<<g256((long long)D * H), 256, 0, stream>>>(W1, W1t, D, H, flags);
    k_transpose_flex<<<g256((long long)H * H), 256, 0, stream>>>(W2, W2t, H, H, flags);
    k_transpose_flex<<<g256((long long)H * K), 256, 0, stream>>>(Wk, Wkt, H, K, flags);

    const int mtiles = (N + 127) / 128;
    // layer 1: g = dinv ⊙ (x @ W1)   (A may be fp32). 128x256 tile: A fetched once.
    k_gemm_bt<2, 2, 4, 8, 0, true, false>
        <<<dim3(1, mtiles), 256, 0, stream>>>(x, W1t, g, dinv, flags, 0, N, H, D);
    k_agg<<<g256((long long)N * 64), 256, 0, stream>>>(g, h, row_ptr, col, dinv, b1, flags, N, 1);
    // layer 2: g = dinv ⊙ (h @ W2)
    k_gemm_bt<2, 2, 4, 8, 0, false, false>
        <<<dim3(1, mtiles), 256, 0, stream>>>(h, W2t, g, dinv, flags, 0, N, H, H);
    k_agg<<<g256((long long)N * 64), 256, 0, stream>>>(g, h, row_ptr, col, dinv, b2, flags, N, 0);
    // logits = h2 @ Wk  -> d_out second half (dtype per flags)
    k_gemm_bt<4, 1, 2, 4, 1, false, true>
        <<<dim3(1, mtiles), 256, 0, stream>>>(h, Wkt, d_out, dinv, flags, NK, N, K, H);
    // softmax -> d_out first half
    k_softmax<<<g256((long long)N * 64), 256, 0, stream>>>(d_out, NK, flags, N);
}

// Round 5
// 709.746 us; speedup vs baseline: 1.4381x; 1.2263x over previous
//
#include <hip/hip_runtime.h>

typedef unsigned short u16;
typedef unsigned int u32;

// ---------- bf16 helpers (bit-level, RNE) ----------
__device__ __forceinline__ float bfl(u32 u) { union { u32 i; float f; } v; v.i = u << 16; return v.f; }
__device__ __forceinline__ float bfh(u32 u) { union { u32 i; float f; } v; v.i = u & 0xffff0000u; return v.f; }
__device__ __forceinline__ float bf2f(u16 u) { union { u32 i; float f; } v; v.i = ((u32)u) << 16; return v.f; }
__device__ __forceinline__ u16 f2bf(float f) {
    union { float f; u32 i; } v; v.f = f;
    u32 r = v.i + 0x7fffu + ((v.i >> 16) & 1u);
    return (u16)(r >> 16);
}

// ---------- async global->LDS 16B ----------
typedef const __attribute__((address_space(1))) unsigned int* gas_u32;
typedef __attribute__((address_space(3))) unsigned int* las_u32;
__device__ __forceinline__ void async_cp16(const void* g, void* l) {
    __builtin_amdgcn_global_load_lds((gas_u32)g, (las_u32)l, 16, 0, 0);
}

// ---------- dtype detection (device-side, no host sync) ----------
__global__ void k_detect(const u32* __restrict__ xw, const int* __restrict__ eiw,
                         const void* __restrict__ ltau, int* __restrict__ flags,
                         int xwords, int E) {
    __shared__ int cf32, ci64nz;
    if (threadIdx.x == 0) { cf32 = 0; ci64nz = 0; }
    __syncthreads();
    int t = threadIdx.x;             // 256 threads
    int xs = xwords / 256;
    u32 w = xw[(size_t)t * xs];
    int e = (int)((w >> 23) & 0xFFu);
    if (e >= 100 && e <= 140) atomicAdd(&cf32, 1);
    int es = E / 256;
    int hw = eiw[2 * (size_t)t * es + 1];   // odd int32 position
    if (hw != 0) atomicAdd(&ci64nz, 1);
    __syncthreads();
    if (t == 0) {
        int f32 = (cf32 >= 192) ? 1 : 0;
        flags[0] = f32;
        flags[1] = (ci64nz == 0) ? 1 : 0;
        ((float*)flags)[2] = f32 ? ((const float*)ltau)[0] : bf2f(((const u16*)ltau)[0]);
    }
}

// ---------- extract src/dst as int32 regardless of edge width ----------
__global__ void k_edges(const int* __restrict__ ei, int* __restrict__ src, int* __restrict__ dst,
                        int e, const int* __restrict__ flags) {
    int i = blockIdx.x * 256 + threadIdx.x;
    if (i >= e) return;
    if (flags[1]) { src[i] = ei[2 * i]; dst[i] = ei[2 * (e + i)]; }   // int64 low words
    else          { src[i] = ei[i];     dst[i] = ei[e + i]; }
}

__global__ void k_zeroi(int* p, int n) {
    int i = blockIdx.x * 256 + threadIdx.x;
    if (i < n) p[i] = 0;
}

// ---------- bucketed CSR build (128 dst/bucket) ----------
// pass 1: per-block LDS histogram of bucket sizes, one global flush per block
__global__ __launch_bounds__(256) void k_bcount(const int* __restrict__ dst, int* __restrict__ bcount,
                                                int e, int nb) {
    __shared__ int h[1024];
    int t = threadIdx.x;
    for (int i = t; i < nb; i += 256) h[i] = 0;
    __syncthreads();
    int chunk = (e + gridDim.x - 1) / gridDim.x;
    int beg = blockIdx.x * chunk;
    int end = beg + chunk; if (end > e) end = e;
    for (int i = beg + t; i < end; i += 256) atomicAdd(&h[dst[i] >> 7], 1);
    __syncthreads();
    for (int i = t; i < nb; i += 256) { int v = h[i]; if (v) atomicAdd(&bcount[i], v); }
}

// pass 2: single-block exclusive scan of bucket counts (nb <= 8192)
__global__ __launch_bounds__(1024) void k_bscan(const int* __restrict__ bcount, int* __restrict__ bbase,
                                                int* __restrict__ bcursor, int nb) {
    int t = threadIdx.x;
    int per = (nb + 1023) >> 10;
    int b0 = t * per;
    int ls[8];
    int s = 0;
#pragma unroll
    for (int j = 0; j < 8; j++) {
        int v = 0;
        if (j < per && b0 + j < nb) v = bcount[b0 + j];
        ls[j] = v; s += v;
    }
    int lane = t & 63, w = t >> 6;
    int inc = s;
    for (int d = 1; d < 64; d <<= 1) { int u = __shfl_up(inc, d); if (lane >= d) inc += u; }
    __shared__ int wsum[16];
    __shared__ int gtot;
    if (lane == 63) wsum[w] = inc;
    __syncthreads();
    if (t == 0) { int a = 0; for (int i = 0; i < 16; i++) { int x = wsum[i]; wsum[i] = a; a += x; } gtot = a; }
    __syncthreads();
    int base = wsum[w] + inc - s;
#pragma unroll
    for (int j = 0; j < 8; j++) {
        if (j < per && b0 + j < nb) { bbase[b0 + j] = base; bcursor[b0 + j] = base; base += ls[j]; }
    }
    if (t == 0) bbase[nb] = gtot;
}

// pass 3: scatter packed (dstl<<25 | src) into bucket-sorted ebuf, block-aggregated cursors
__global__ __launch_bounds__(256) void k_bscatter(const int* __restrict__ src, const int* __restrict__ dst,
                                                  int* __restrict__ bcursor, u32* __restrict__ ebuf,
                                                  int e, int nb) {
    __shared__ int h[1024];
    __shared__ int lbase[1024];
    int t = threadIdx.x;
    for (int i = t; i < nb; i += 256) h[i] = 0;
    __syncthreads();
    int chunk = (e + gridDim.x - 1) / gridDim.x;
    int beg = blockIdx.x * chunk;
    int end = beg + chunk; if (end > e) end = e;
    for (int i = beg + t; i < end; i += 256) atomicAdd(&h[dst[i] >> 7], 1);
    __syncthreads();
    for (int i = t; i < nb; i += 256) {
        int v = h[i];
        lbase[i] = v ? atomicAdd(&bcursor[i], v) : 0;
        h[i] = 0;                    // reuse as local cursor
    }
    __syncthreads();
    for (int i = beg + t; i < end; i += 256) {
        int d = dst[i];
        int b = d >> 7;
        int p = lbase[b] + atomicAdd(&h[b], 1);
        ebuf[p] = ((u32)(d & 127) << 25) | (u32)src[i];
    }
}

// pass 4: per-bucket CSR finalize: hist+scan in LDS -> row_ptr, dinv, dense col writes
__global__ __launch_bounds__(256) void k_bcsr(const u32* __restrict__ ebuf, const int* __restrict__ bbase,
                                              int* __restrict__ row_ptr, float* __restrict__ dinv,
                                              int* __restrict__ col, int n, int nb, int e) {
    __shared__ int hist[128], sc[128], cur[128];
    int b = blockIdx.x, t = threadIdx.x;
    if (t < 128) hist[t] = 0;
    __syncthreads();
    int beg = bbase[b], end = bbase[b + 1];
    for (int j = beg + t; j < end; j += 256) atomicAdd(&hist[ebuf[j] >> 25], 1);
    __syncthreads();
    if (t < 128) sc[t] = hist[t];
    __syncthreads();
    for (int d = 1; d < 128; d <<= 1) {
        int v = 0;
        if (t < 128 && t >= d) v = sc[t - d];
        __syncthreads();
        if (t < 128) sc[t] += v;
        __syncthreads();
    }
    if (t < 128) {
        int node = (b << 7) + t;
        if (node < n) {
            int ex = sc[t] - hist[t];
            row_ptr[node] = beg + ex;
            dinv[node] = rsqrtf((float)(hist[t] + 1));   // +1 self-loop
            cur[t] = ex;
        }
    }
    if (b == 0 && t == 0) row_ptr[n] = e;
    __syncthreads();
    for (int j = beg + t; j < end; j += 256) {
        u32 ev = ebuf[j];
        int dl = (int)(ev >> 25);
        int p = atomicAdd(&cur[dl], 1);
        col[beg + p] = (int)(ev & 0x1FFFFFFu);
    }
}

// transpose weight to Bt layout, converting to bf16 if needed
__global__ void k_transpose_flex(const void* __restrict__ in, u16* __restrict__ out,
                                 int R, int C, const int* __restrict__ flags) {
    int idx = blockIdx.x * 256 + threadIdx.x;
    if (idx >= R * C) return;
    u16 v = flags[0] ? f2bf(((const float*)in)[idx]) : ((const u16*)in)[idx];
    int r = idx / C, c = idx % C;
    out[(size_t)c * R + r] = v;
}

// ---------- MFMA bf16 GEMM, B-transposed input, double-buffered LDS ----------
typedef __bf16 bf16x8 __attribute__((ext_vector_type(8)));
typedef float floatx4 __attribute__((ext_vector_type(4)));

// C[M,Nd] = A[M,Kd] @ Bt[Nd,Kd]^T
// MODE 0: scale row by dinv, store bf16.  MODE 1: plain store at obase (flex dtype).
// AFLEX: A may be fp32 (per flags[0]).   OFLEX: output may be fp32 (per flags[0]).
// 64-row tiles + 40KB LDS dbuf -> 4 blocks/CU for TLP; prefetch issued after
// barrier so stage(s+1) HBM latency overlaps compute(s).
template <int WROWS, int WCOLS, int TM, int TN, int MODE, bool AFLEX, bool OFLEX>
__global__ __launch_bounds__(256, 4) void k_gemm_bt(const void* __restrict__ A,
                                                    const u16* __restrict__ Bt,
                                                    void* __restrict__ C,
                                                    const float* __restrict__ dinv,
                                                    const int* __restrict__ flags,
                                                    long long obase,
                                                    int M, int Nd, int Kd) {
    constexpr int BM = WROWS * TM * 16;
    constexpr int BN = WCOLS * TN * 16;
    constexpr int BK = 32;
    __shared__ u16 As[2][BM][BK];
    __shared__ u16 Bs[2][BN][BK];
    const int af32 = AFLEX ? flags[0] : 0;
    const int of32 = OFLEX ? flags[0] : 0;
    const int tid = threadIdx.x;
    const int m0 = blockIdx.y * BM;
    const int n0 = blockIdx.x * BN;
    const int lane = tid & 63;
    const int wave = tid >> 6;
    const int wm = wave / WCOLS;
    const int wn = wave % WCOLS;
    const int mrow = lane & 15;
    const int quad = lane >> 4;

    floatx4 acc[TM][TN];
#pragma unroll
    for (int i = 0; i < TM; i++)
#pragma unroll
        for (int j = 0; j < TN; j++) { floatx4 z = {0.f, 0.f, 0.f, 0.f}; acc[i][j] = z; }

    auto stage = [&](int kk, int buf) {
        if (AFLEX && af32) {
#pragma unroll
            for (int idx = tid * 8; idx < BM * BK; idx += 256 * 8) {
                int r = idx >> 5, k = idx & 31;
                int gr = m0 + r;
                u16 t8[8] = {0, 0, 0, 0, 0, 0, 0, 0};
                if (gr < M) {
                    const float* ap = (const float*)A + (size_t)gr * Kd + kk + k;
                    float4 f0 = *(const float4*)ap;
                    float4 f1 = *(const float4*)(ap + 4);
                    t8[0] = f2bf(f0.x); t8[1] = f2bf(f0.y); t8[2] = f2bf(f0.z); t8[3] = f2bf(f0.w);
                    t8[4] = f2bf(f1.x); t8[5] = f2bf(f1.y); t8[6] = f2bf(f1.z); t8[7] = f2bf(f1.w);
                }
                *(int4*)&As[buf][r][k] = *(const int4*)t8;
            }
#pragma unroll
            for (int idx = tid * 8; idx < BN * BK; idx += 256 * 8) {
                int r = idx >> 5, k = idx & 31;
                int4 v = *(const int4*)(Bt + (size_t)(n0 + r) * Kd + kk + k);
                *(int4*)&Bs[buf][r][k] = v;
            }
        } else {
#pragma unroll
            for (int idx = tid * 8; idx < BM * BK; idx += 256 * 8) {
                int r = idx >> 5, k = idx & 31;
                int gr = m0 + r;
                if (gr >= M) gr = M - 1;   // clamp: garbage only reaches discarded OOB C-rows
                async_cp16((const u16*)A + (size_t)gr * Kd + kk + k, &As[buf][r][k]);
            }
#pragma unroll
            for (int idx = tid * 8; idx < BN * BK; idx += 256 * 8) {
                int r = idx >> 5, k = idx & 31;
                async_cp16(Bt + (size_t)(n0 + r) * Kd + kk + k, &Bs[buf][r][k]);
            }
        }
    };

    const int steps = Kd / BK;
    stage(0, 0);
    for (int s = 0; s < steps; s++) {
        __syncthreads();                       // drains stage(s)
        if (s + 1 < steps) stage((s + 1) * BK, (s + 1) & 1);   // overlaps compute below
        const int b = s & 1;
        bf16x8 af[TM], bfr[TN];
#pragma unroll
        for (int i = 0; i < TM; i++)
            af[i] = *(const bf16x8*)&As[b][wm * TM * 16 + i * 16 + mrow][quad * 8];
#pragma unroll
        for (int j = 0; j < TN; j++)
            bfr[j] = *(const bf16x8*)&Bs[b][wn * TN * 16 + j * 16 + mrow][quad * 8];
#pragma unroll
        for (int i = 0; i < TM; i++)
#pragma unroll
            for (int j = 0; j < TN; j++)
                acc[i][j] = __builtin_amdgcn_mfma_f32_16x16x32_bf16(af[i], bfr[j], acc[i][j], 0, 0, 0);
    }

#pragma unroll
    for (int i = 0; i < TM; i++) {
#pragma unroll
        for (int r = 0; r < 4; r++) {
            int grow = m0 + wm * TM * 16 + i * 16 + quad * 4 + r;
            if (grow < M) {
                float scale = (MODE == 0) ? dinv[grow] : 1.0f;
#pragma unroll
                for (int j = 0; j < TN; j++) {
                    int gcol = n0 + wn * TN * 16 + j * 16 + mrow;
                    float val = acc[i][j][r] * scale;
                    long long cidx = obase + (long long)grow * Nd + gcol;
                    if (OFLEX && of32) ((float*)C)[cidx] = val;
                    else               ((u16*)C)[cidx] = f2bf(val);
                }
            }
        }
    }
}

// ---------- CSR gather-aggregate: one wave per node, H=256 (4 bf16/lane) ----------
__global__ __launch_bounds__(256) void k_agg(const u16* __restrict__ g, u16* __restrict__ out,
                                             const int* __restrict__ row_ptr,
                                             const int* __restrict__ col,
                                             const float* __restrict__ dinv,
                                             const void* __restrict__ bias,
                                             const int* __restrict__ flags,
                                             int n, int do_relu) {
    int wid = (int)((blockIdx.x * 256 + threadIdx.x) >> 6);
    int lane = threadIdx.x & 63;
    if (wid >= n) return;
    const u16* gp = g + (size_t)lane * 4;
    uint2 rv = *(const uint2*)(gp + (size_t)wid * 256);   // self term g[dst]
    float a0 = bfl(rv.x), a1 = bfh(rv.x), a2 = bfl(rv.y), a3 = bfh(rv.y);
    int beg = row_ptr[wid], end = row_ptr[wid + 1];
    for (int base = beg; base < end; base += 64) {
        int m = end - base; if (m > 64) m = 64;
        int ci = (base + lane < end) ? col[base + lane] : 0;   // 1 coalesced load / chunk
        int j = 0;
        for (; j + 8 <= m; j += 8) {
            uint2 v[8];
#pragma unroll
            for (int q = 0; q < 8; q++) {
                int s = __shfl(ci, j + q);
                v[q] = *(const uint2*)(gp + (size_t)s * 256);
            }
#pragma unroll
            for (int q = 0; q < 8; q++) {
                a0 += bfl(v[q].x); a1 += bfh(v[q].x);
                a2 += bfl(v[q].y); a3 += bfh(v[q].y);
            }
        }
        for (; j < m; j++) {
            int s = __shfl(ci, j);
            uint2 v = *(const uint2*)(gp + (size_t)s * 256);
            a0 += bfl(v.x); a1 += bfh(v.x); a2 += bfl(v.y); a3 += bfh(v.y);
        }
    }
    float dv = dinv[wid];
    float b0, b1, b2, b3;
    if (flags[0]) {
        float4 q = ((const float4*)bias)[lane];
        b0 = q.x; b1 = q.y; b2 = q.z; b3 = q.w;
    } else {
        uint2 bv = ((const uint2*)bias)[lane];
        b0 = bfl(bv.x); b1 = bfh(bv.x); b2 = bfl(bv.y); b3 = bfh(bv.y);
    }
    a0 = a0 * dv + b0;
    a1 = a1 * dv + b1;
    a2 = a2 * dv + b2;
    a3 = a3 * dv + b3;
    if (do_relu) {
        a0 = fmaxf(a0, 0.f); a1 = fmaxf(a1, 0.f); a2 = fmaxf(a2, 0.f); a3 = fmaxf(a3, 0.f);
    }
    uint2 o;
    o.x = (u32)f2bf(a0) | ((u32)f2bf(a1) << 16);
    o.y = (u32)f2bf(a2) | ((u32)f2bf(a3) << 16);
    *(uint2*)(out + (size_t)wid * 256 + (size_t)lane * 4) = o;
}

// ---------- softmax over K=64: logits at element offset NK inside d_out ----------
__global__ __launch_bounds__(256) void k_softmax(void* __restrict__ out, long long NK,
                                                 const int* __restrict__ flags, int n) {
    int wid = (int)((blockIdx.x * 256 + threadIdx.x) >> 6);
    int lane = threadIdx.x & 63;
    if (wid >= n) return;
    int f32o = flags[0];
    float lt = ((const float*)flags)[2];
    float inv_tau = __expf(-lt);
    long long li = NK + (long long)wid * 64 + lane;
    float x = f32o ? ((const float*)out)[li] : bf2f(((const u16*)out)[li]);
    x *= inv_tau;
    float m = x;
    for (int d = 32; d; d >>= 1) m = fmaxf(m, __shfl_xor(m, d));
    float e = __expf(x - m);
    float s = e;
    for (int d = 32; d; d >>= 1) s += __shfl_xor(s, d);
    float r = e / s;
    long long si = (long long)wid * 64 + lane;
    if (f32o) ((float*)out)[si] = r;
    else      ((u16*)out)[si] = f2bf(r);
}

extern "C" void kernel_launch(void* const* d_in, const int* in_sizes, int n_in,
                              void* d_out, int out_size, void* d_ws, size_t ws_size,
                              hipStream_t stream) {
    const void* x    = d_in[0];
    const int*  ei   = (const int*)d_in[1];
    const void* W1   = d_in[2];
    const void* b1   = d_in[3];
    const void* W2   = d_in[4];
    const void* b2   = d_in[5];
    const void* Wk   = d_in[6];
    const void* ltau = d_in[7];
    const int D = 512, H = 256, K = 64;
    const int N = in_sizes[0] / D;
    const int E = in_sizes[1] / 2;
    const long long NK = (long long)N * K;
    const int nb = (N + 127) >> 7;           // 128 dst per bucket

    // ---- workspace: two big ping-pong buffers + flags ----
    u16* g = (u16*)d_ws;                      // N*H bf16 = 51.2 MB
    u16* h = g + (size_t)N * H;               // N*H bf16 = 51.2 MB
    int* flags = (int*)(h + (size_t)N * H);   // 256 B
    // prep-phase overlays inside g (dead before GEMM1 writes g)
    int* srcv = (int*)g;
    int* dstv = srcv + E;
    u32* ebuf = (u32*)(dstv + E);

    // ---- d_out scratch (S-region is dead until the final softmax) ----
    size_t ooff = 0;
    auto oalloc = [&](size_t bytes) -> char* {
        char* p = (char*)d_out + ooff;
        ooff += (bytes + 255) & ~(size_t)255;
        return p;
    };
    int*   col     = (int*)oalloc((size_t)E * 4);
    float* dinv    = (float*)oalloc((size_t)N * 4);
    int*   row_ptr = (int*)oalloc((size_t)(N + 1) * 4);
    int*   bcount  = (int*)oalloc((size_t)nb * 4);
    int*   bbase   = (int*)oalloc((size_t)(nb + 1) * 4);
    int*   bcursor = (int*)oalloc((size_t)nb * 4);
    u16*   W1t     = (u16*)oalloc((size_t)D * H * 2);
    u16*   W2t     = (u16*)oalloc((size_t)H * H * 2);
    u16*   Wkt     = (u16*)oalloc((size_t)H * K * 2);
    // total ~= 7.7 MB < S-region (N*K*2 bytes = 12.8 MB)

    auto g256 = [](long long n) { return (int)((n + 255) / 256); };

    k_detect<<<1, 256, 0, stream>>>((const u32*)x, ei, ltau, flags, in_sizes[0] / 2, E);
    k_edges<<<g256(E), 256, 0, stream>>>(ei, srcv, dstv, E, flags);
    k_zeroi<<<g256(nb), 256, 0, stream>>>(bcount, nb);
    k_bcount<<<256, 256, 0, stream>>>(dstv, bcount, E, nb);
    k_bscan<<<1, 1024, 0, stream>>>(bcount, bbase, bcursor, nb);
    k_bscatter<<<256, 256, 0, stream>>>(srcv, dstv, bcursor, ebuf, E, nb);
    k_bcsr<<<nb, 256, 0, stream>>>(ebuf, bbase, row_ptr, dinv, col, N, nb, E);

    k_transpose_flex<<<g256((long long)D * H), 256, 0, stream>>>(W1, W1t, D, H, flags);
    k_transpose_flex<<<g256((long long)H * H), 256, 0, stream>>>(W2, W2t, H, H, flags);
    k_transpose_flex<<<g256((long long)H * K), 256, 0, stream>>>(Wk, Wkt, H, K, flags);

    const int m64 = (N + 63) / 64;
    // layer 1: g = dinv ⊙ (x @ W1)   64x256 tile, 40KB LDS dbuf, 4 blocks/CU
    k_gemm_bt<1, 4, 4, 4, 0, true, false>
        <<<dim3(1, m64), 256, 0, stream>>>(x, W1t, g, dinv, flags, 0, N, H, D);
    k_agg<<<g256((long long)N * 64), 256, 0, stream>>>(g, h, row_ptr, col, dinv, b1, flags, N, 1);
    // layer 2: g = dinv ⊙ (h @ W2)
    k_gemm_bt<1, 4, 4, 4, 0, false, false>
        <<<dim3(1, m64), 256, 0, stream>>>(h, W2t, g, dinv, flags, 0, N, H, H);
    k_agg<<<g256((long long)N * 64), 256, 0, stream>>>(g, h, row_ptr, col, dinv, b2, flags, N, 0);
    // logits = h2 @ Wk  -> d_out second half (dtype per flags)
    k_gemm_bt<1, 4, 4, 1, 1, false, true>
        <<<dim3(1, m64), 256, 0, stream>>>(h, Wkt, d_out, dinv, flags, NK, N, K, H);
    // softmax -> d_out first half
    k_softmax<<<g256((long long)N * 64), 256, 0, stream>>>(d_out, NK, flags, N);
}